// Round 1
// baseline (38.724 us; speedup 1.0000x reference)
//
#include <hip/hip_runtime.h>
#include <stdint.h>

#define BB      512
#define NCROPS  5
#define TT      8192
#define THREADS 256
#define EPT     32   // elements per thread = TT/THREADS
#define VPT     8    // float4 per thread per crop

// Order-preserving f32 -> u32 transform (ascending)
__device__ __forceinline__ uint32_t f2ord(float f) {
    uint32_t b = __float_as_uint(f);
    return (b & 0x80000000u) ? ~b : (b | 0x80000000u);
}
__device__ __forceinline__ float ord2f(uint32_t u) {
    uint32_t b = (u & 0x80000000u) ? (u & 0x7FFFFFFFu) : ~u;
    return __uint_as_float(b);
}

__global__ __launch_bounds__(THREADS) void topk_loss_rows(
    const float* __restrict__ scores, const int* __restrict__ label,
    const int* __restrict__ seqlen, float* __restrict__ row_loss)
{
    const int b    = blockIdx.x;
    const int tid  = threadIdx.x;
    const int lane = tid & 63;
    const int wave = tid >> 6;

    const int sl = seqlen[b];
    const int lb = label[b];
    const int k  = (lb == 0) ? 1 : (sl / 16 + 1);   // always <= sl

    // ---- load + crop-mean, keep order keys in registers ----
    const float* base = scores + (size_t)b * NCROPS * TT;
    uint32_t u[EPT];
    #pragma unroll
    for (int j = 0; j < VPT; ++j) {
        const int t4 = tid + j * THREADS;        // float4 index within row
        float4 acc;
        {
            const float4 v0 = *reinterpret_cast<const float4*>(base + 0 * TT + 4 * t4);
            acc = v0;
        }
        #pragma unroll
        for (int c = 1; c < NCROPS; ++c) {
            const float4 v = *reinterpret_cast<const float4*>(base + (size_t)c * TT + 4 * t4);
            acc.x += v.x; acc.y += v.y; acc.z += v.z; acc.w += v.w;
        }
        const int t0 = 4 * t4;
        const float m0 = acc.x * 0.2f;
        const float m1 = acc.y * 0.2f;
        const float m2 = acc.z * 0.2f;
        const float m3 = acc.w * 0.2f;
        u[4*j+0] = (t0 + 0 < sl) ? f2ord(m0) : 0u;
        u[4*j+1] = (t0 + 1 < sl) ? f2ord(m1) : 0u;
        u[4*j+2] = (t0 + 2 < sl) ? f2ord(m2) : 0u;
        u[4*j+3] = (t0 + 3 < sl) ? f2ord(m3) : 0u;
    }

    // ---- binary search on key bits for the k-th largest ----
    // invariant: cnt_ge(lo) >= k
    __shared__ int   s_w[4];
    __shared__ float s_s[4];
    __shared__ int   s_c[4];

    uint32_t lo = 0u, hi = 0xFFFFFFFFu;
    while (lo < hi) {
        const uint32_t d   = hi - lo;
        const uint32_t mid = lo + (d >> 1) + (d & 1u);   // upper mid, no overflow
        int c = 0;
        #pragma unroll
        for (int i = 0; i < EPT; ++i) c += (u[i] >= mid) ? 1 : 0;
        #pragma unroll
        for (int off = 32; off; off >>= 1) c += __shfl_down(c, off);
        if (lane == 0) s_w[wave] = c;
        __syncthreads();
        const int total = s_w[0] + s_w[1] + s_w[2] + s_w[3];
        if (total >= k) lo = mid; else hi = mid - 1;
        __syncthreads();
    }
    const uint32_t kth = lo;

    // ---- sum of elements strictly greater than kth ----
    float sg = 0.f;
    int   cg = 0;
    #pragma unroll
    for (int i = 0; i < EPT; ++i) {
        if (u[i] > kth) { sg += ord2f(u[i]); cg++; }
    }
    #pragma unroll
    for (int off = 32; off; off >>= 1) {
        sg += __shfl_down(sg, off);
        cg += __shfl_down(cg, off);
    }
    if (lane == 0) { s_s[wave] = sg; s_c[wave] = cg; }
    __syncthreads();

    if (tid == 0) {
        const float sum_g = s_s[0] + s_s[1] + s_s[2] + s_s[3];
        const int   cnt_g = s_c[0] + s_c[1] + s_c[2] + s_c[3];
        const float kf    = ord2f(kth);
        const float topk  = sum_g + (float)(k - cnt_g) * kf;
        const float v     = topk / (float)k;
        const float y     = (float)lb;
        // logaddexp(0, v) stable
        const float la    = fmaxf(v, 0.f) + log1pf(expf(-fabsf(v)));
        row_loss[b] = la - v * y;
    }
}

__global__ __launch_bounds__(256) void reduce_loss(
    const float* __restrict__ row_loss, float* __restrict__ out)
{
    const int tid = threadIdx.x;
    float v = row_loss[tid] + row_loss[tid + 256];
    #pragma unroll
    for (int off = 32; off; off >>= 1) v += __shfl_down(v, off);
    __shared__ float s[4];
    if ((tid & 63) == 0) s[tid >> 6] = v;
    __syncthreads();
    if (tid == 0) out[0] = (s[0] + s[1] + s[2] + s[3]) * (1.0f / 512.0f);
}

extern "C" void kernel_launch(void* const* d_in, const int* in_sizes, int n_in,
                              void* d_out, int out_size, void* d_ws, size_t ws_size,
                              hipStream_t stream) {
    const float* scores = (const float*)d_in[0];
    const int*   label  = (const int*)d_in[1];
    const int*   seqlen = (const int*)d_in[2];
    float* out      = (float*)d_out;
    float* row_loss = (float*)d_ws;   // 512 floats

    topk_loss_rows<<<BB, THREADS, 0, stream>>>(scores, label, seqlen, row_loss);
    reduce_loss<<<1, 256, 0, stream>>>(row_loss, out);
}